// Round 10
// baseline (1180.078 us; speedup 1.0000x reference)
//
#include <hip/hip_runtime.h>
#include <stdint.h>

#define F 16
#define CDIM 320
#define DDIM 4096
#define NSEQ 8192
#define WPB 4
#define THREADS (WPB*64)
#define NT 20
#define KS 10

typedef __attribute__((ext_vector_type(8))) short short8;
typedef __attribute__((ext_vector_type(4))) float f32x4;

__device__ __forceinline__ unsigned short f2bf(float f) {
    union { float f; uint32_t u; } v; v.f = f;
    uint32_t r = v.u + 0x7FFFu + ((v.u >> 16) & 1u);   // RTNE
    return (unsigned short)(r >> 16);
}
__device__ __forceinline__ float bf2f(unsigned short h) {
    union { uint32_t u; float f; } v; v.u = ((uint32_t)h) << 16;
    return v.f;
}
// [16][320] bf16 tile swizzle, row stride 640 B = 40 16B-chunks = 5 groups of 8.
// chunk ^ (row&7) is bijective per row and always in-bounds.
__device__ __forceinline__ int swz(int row, int b) {
    return row * 640 + (b ^ ((row & 7) << 4));
}

// One-time: pack Wq/Wk/Wv/Wo (fp32 row-major [320][320]) into bf16 B-fragment
// order. Fragment (m, nt, ks) is a 1KB block: lane (g,lr) holds
// W[nt*16+lr][ks*32+g*8 .. +7]. Byte offset = ((m*NT+nt)*KS+ks)*1024 + lane*16.
__global__ __launch_bounds__(256)
void pack_weights_kernel(const float* __restrict__ Wq, const float* __restrict__ Wk,
                         const float* __restrict__ Wv, const float* __restrict__ Wo,
                         char* __restrict__ pk)
{
    const int t = blockIdx.x * 256 + threadIdx.x;
    if (t >= 4 * NT * KS * 64) return;
    const int lane = t & 63;
    const int rest = t >> 6;
    const int ks = rest % KS;
    const int nt = (rest / KS) % NT;
    const int m  = rest / (KS * NT);
    const float* W = (m == 0) ? Wq : (m == 1) ? Wk : (m == 2) ? Wv : Wo;
    const int g = lane >> 4, lr = lane & 15;
    const float* src = W + (size_t)(nt * 16 + lr) * CDIM + ks * 32 + g * 8;
    const f32x4 a = *(const f32x4*)src;
    const f32x4 b = *(const f32x4*)(src + 4);
    float vals[8] = {a[0], a[1], a[2], a[3], b[0], b[1], b[2], b[3]};
    short8 o;
#pragma unroll
    for (int j = 0; j < 8; ++j) o[j] = (short)f2bf(vals[j]);
    *(short8*)(pk + (size_t)t * 16) = o;
}

// Spill post-mortem (R3-R5,R7-R9): two mechanisms, both addressed here.
//  (1) NO pointers to local arrays (R9's `float* s = h2?s1:s0` -> scratch).
//      s[2][16] is statically indexed under fully-unrolled h2.
//  (2) amdgpu_waves_per_eu(2,3): max=3 stops the scheduler from targeting
//      the LDS-implied 4 waves/SIMD (pressure limit 128 -> spiral of spills);
//      limit becomes ~170. If allocation lands <=128 anyway, HW still runs
//      4 waves/SIMD (LDS allows 4 blocks/CU).
//  Passes stay top-level straight-line; proj uses unroll 1 (10-load batches).
__global__ __attribute__((amdgpu_waves_per_eu(2, 3))) __launch_bounds__(THREADS)
void temporal_attn_kernel(const float* __restrict__ hs,
                          const char* __restrict__ wpk,
                          const float* __restrict__ bo,
                          float* __restrict__ out)
{
    extern __shared__ __align__(16) char smem[];
    const int tid  = threadIdx.x;
    const int lane = tid & 63;
    const int wave = tid >> 6;
    const int g    = lane >> 4;
    const int lr   = lane & 15;

    const int seq = blockIdx.x * WPB + wave;
    const int bi  = seq >> 12;
    const int di  = seq & (DDIM - 1);

    char* const buf = smem + wave * 10240;   // Q -> K -> V -> attn-out
    const char* const wl = wpk + lane * 16;

    // ---- load x rows, add PE, convert to bf16 A-fragments (40 VGPR) ----
    const float* xrow = hs + ((size_t)(bi * F + lr) * DDIM + di) * CDIM;
    short8 axk[KS];
#pragma unroll
    for (int ks = 0; ks < KS; ++ks) {
        const int k0 = ks * 32 + g * 8;
        const f32x4 a = __builtin_nontemporal_load((const f32x4*)(xrow + k0));
        const f32x4 b = __builtin_nontemporal_load((const f32x4*)(xrow + k0 + 4));
        float xv[8] = {a[0], a[1], a[2], a[3], b[0], b[1], b[2], b[3]};
#pragma unroll
        for (int jj = 0; jj < 4; ++jj) {
            const float c0 = (float)(k0 + 2 * jj);
            const float dv = __expf(c0 * -0.028782313662425575f); // -ln(1e4)/320
            const float ang = (float)lr * dv;                      // pos = frame
            xv[2 * jj]     += __sinf(ang);
            xv[2 * jj + 1] += __cosf(ang);
        }
        short8 t;
#pragma unroll
        for (int j = 0; j < 8; ++j) t[j] = (short)f2bf(xv[j]);
        axk[ks] = t;
    }

    // ---- full-width projection: inline loads feed MFMAs, one tile at a time ----
    auto proj = [&](int m, char* dst) {
#pragma unroll 1
        for (int nt = 0; nt < NT; ++nt) {
            f32x4 acc = {0.f, 0.f, 0.f, 0.f};
#pragma unroll
            for (int ks = 0; ks < KS; ++ks) {
                short8 b = *(const short8*)(wl + (size_t)((m * NT + nt) * KS + ks) * 1024);
                acc = __builtin_amdgcn_mfma_f32_16x16x32_bf16(axk[ks], b, acc, 0, 0, 0);
            }
#pragma unroll
            for (int r = 0; r < 4; ++r)
                *(short*)(dst + swz(g * 4 + r, (nt * 16 + lr) * 2)) = (short)f2bf(acc[r]);
        }
    };

    proj(0, buf);                        // Q -> buf
    short8 qreg[2][5];                   // statically indexed (unrolled regions)
#pragma unroll
    for (int h2 = 0; h2 < 2; ++h2)
#pragma unroll
        for (int j5 = 0; j5 < 5; ++j5)
            qreg[h2][j5] = *(const short8*)(buf + swz(lr, (g + 4 * h2) * 80 + j5 * 16));

    proj(1, buf);                        // K overwrites Q (qreg extracted)

    // ---- scores + softmax for BOTH halves before V overwrites K ----
    // s[2][16] statically indexed only (no pointer selects -> stays in VGPRs).
    const float scale = 0.15811388300841897f;  // 40^-0.5
    float s[2][F];
#pragma unroll
    for (int h2 = 0; h2 < 2; ++h2)
#pragma unroll
        for (int kk = 0; kk < F; ++kk) s[h2][kk] = 0.f;

#pragma unroll
    for (int h2 = 0; h2 < 2; ++h2) {
        const int cb = (g + 4 * h2) * 80;
#pragma unroll
        for (int j5 = 0; j5 < 5; ++j5) {
            float qf[8];
#pragma unroll
            for (int j = 0; j < 8; ++j) qf[j] = bf2f((unsigned short)qreg[h2][j5][j]);
#pragma unroll
            for (int kk = 0; kk < F; ++kk) {
                short8 k8 = *(const short8*)(buf + swz(kk, cb + j5 * 16));
#pragma unroll
                for (int j = 0; j < 8; ++j) s[h2][kk] += qf[j] * bf2f((unsigned short)k8[j]);
            }
        }
        float m = -1e30f;
#pragma unroll
        for (int kk = 0; kk < F; ++kk) {
            s[h2][kk] = (kk <= lr) ? s[h2][kk] * scale : -1e30f;
            m = fmaxf(m, s[h2][kk]);
        }
        float sum = 0.f;
#pragma unroll
        for (int kk = 0; kk < F; ++kk) { s[h2][kk] = __expf(s[h2][kk] - m); sum += s[h2][kk]; }
        const float inv = 1.f / sum;
#pragma unroll
        for (int kk = 0; kk < F; ++kk) s[h2][kk] *= inv;
    }

    proj(2, buf);                        // V overwrites K (scores in regs)

    // ---- PV, in-place per chunk: read all 16 rows of chunk j5, then write
    // row lr of chunk j5; later chunks untouched (bijective per-row swizzle) ----
#pragma unroll
    for (int h2 = 0; h2 < 2; ++h2) {
        const int cb = (g + 4 * h2) * 80;
#pragma unroll
        for (int j5 = 0; j5 < 5; ++j5) {
            float a8[8];
#pragma unroll
            for (int j = 0; j < 8; ++j) a8[j] = 0.f;
#pragma unroll
            for (int kk = 0; kk < F; ++kk) {
                short8 v8 = *(const short8*)(buf + swz(kk, cb + j5 * 16));
#pragma unroll
                for (int j = 0; j < 8; ++j) a8[j] += s[h2][kk] * bf2f((unsigned short)v8[j]);
            }
            short8 t;
#pragma unroll
            for (int j = 0; j < 8; ++j) t[j] = (short)f2bf(a8[j]);
            *(short8*)(buf + swz(lr, cb + j5 * 16)) = t;
        }
    }

    // ---- output projection: out = ao @ Wo.T + bo, paired 128B-line stores ----
    short8 aof[KS];
#pragma unroll
    for (int ks = 0; ks < KS; ++ks)
        aof[ks] = *(const short8*)(buf + swz(lr, ks * 64 + g * 16));

#pragma unroll 1
    for (int np = 0; np < 10; ++np) {
        f32x4 a0 = {0.f, 0.f, 0.f, 0.f};
        f32x4 a1 = {0.f, 0.f, 0.f, 0.f};
#pragma unroll
        for (int ks = 0; ks < KS; ++ks) {
            short8 b = *(const short8*)(wl + (size_t)((3 * NT + 2 * np) * KS + ks) * 1024);
            a0 = __builtin_amdgcn_mfma_f32_16x16x32_bf16(aof[ks], b, a0, 0, 0, 0);
        }
#pragma unroll
        for (int ks = 0; ks < KS; ++ks) {
            short8 b = *(const short8*)(wl + (size_t)((3 * NT + 2 * np + 1) * KS + ks) * 1024);
            a1 = __builtin_amdgcn_mfma_f32_16x16x32_bf16(aof[ks], b, a1, 0, 0, 0);
        }
        const int c0 = 2 * np * 16 + lr;
        const int c1 = c0 + 16;
        const float bias0 = bo[c0];
        const float bias1 = bo[c1];
        // rows are 1280B-aligned; pair np covers bytes [np*128, +128) of each
        // row: exactly one full 128B line per output row, no write amp.
#pragma unroll
        for (int r = 0; r < 4; ++r) {
            float* rowp = out + ((size_t)(bi * F + g * 4 + r) * DDIM + di) * CDIM;
            rowp[c0] = a0[r] + bias0;
            rowp[c1] = a1[r] + bias1;
        }
    }
}

extern "C" void kernel_launch(void* const* d_in, const int* in_sizes, int n_in,
                              void* d_out, int out_size, void* d_ws, size_t ws_size,
                              hipStream_t stream) {
    const float* hs = (const float*)d_in[0];
    const float* Wq = (const float*)d_in[1];
    const float* Wk = (const float*)d_in[2];
    const float* Wv = (const float*)d_in[3];
    const float* Wo = (const float*)d_in[4];
    const float* bo = (const float*)d_in[5];
    float* out = (float*)d_out;
    char* wpk = (char*)d_ws;   // 4*200*1024 = 819200 B of packed bf16 weights

    pack_weights_kernel<<<dim3((4 * NT * KS * 64 + 255) / 256), dim3(256), 0, stream>>>(
        Wq, Wk, Wv, Wo, wpk);

    const int lds = WPB * 10240;   // 40960 B -> up to 4 blocks/CU by LDS
    (void)hipFuncSetAttribute((const void*)temporal_attn_kernel,
                              hipFuncAttributeMaxDynamicSharedMemorySize, lds);
    temporal_attn_kernel<<<dim3(NSEQ / WPB), dim3(THREADS), lds, stream>>>(
        hs, wpk, bo, out);
}

// Round 11
// 274.789 us; speedup vs baseline: 4.2945x; 4.2945x over previous
//
#include <hip/hip_runtime.h>
#include <stdint.h>

#define F 16
#define CDIM 320
#define DDIM 4096
#define NSEQ 8192
#define WPB 4
#define THREADS 256
#define NT 20
#define KS 10

typedef __attribute__((ext_vector_type(8))) short short8;
typedef __attribute__((ext_vector_type(4))) float f32x4;

__device__ __forceinline__ unsigned short f2bf(float f) {
    union { float f; uint32_t u; } v; v.f = f;
    uint32_t r = v.u + 0x7FFFu + ((v.u >> 16) & 1u);   // RTNE
    return (unsigned short)(r >> 16);
}
__device__ __forceinline__ float bf2f(unsigned short h) {
    union { uint32_t u; float f; } v; v.u = ((uint32_t)h) << 16;
    return v.f;
}
// XOR swizzle inside a [16][320] bf16 row-major tile (row stride 640 B).
// 16B chunks; chunk ^ (row&7) is a bijection per row -> disjoint regions
// stay disjoint under the swizzle.
__device__ __forceinline__ int swz(int row, int b) {
    return row * 640 + (b ^ ((row & 7) << 4));
}

// One-time: pack Wq/Wk/Wv/Wo (fp32 row-major [320][320]) into bf16 B-fragment
// order. Fragment (m, nt, ks) is a 1KB block: lane (g,lr) holds
// W[nt*16+lr][ks*32+g*8 .. +7]. Byte offset = ((m*NT+nt)*KS+ks)*1024 + lane*16.
__global__ __launch_bounds__(256)
void pack_weights_kernel(const float* __restrict__ Wq, const float* __restrict__ Wk,
                         const float* __restrict__ Wv, const float* __restrict__ Wo,
                         char* __restrict__ pk)
{
    const int t = blockIdx.x * 256 + threadIdx.x;
    if (t >= 4 * NT * KS * 64) return;
    const int lane = t & 63;
    const int rest = t >> 6;
    const int ks = rest % KS;
    const int nt = (rest / KS) % NT;
    const int m  = rest / (KS * NT);
    const float* W = (m == 0) ? Wq : (m == 1) ? Wk : (m == 2) ? Wv : Wo;
    const int g = lane >> 4, lr = lane & 15;
    const float* src = W + (size_t)(nt * 16 + lr) * CDIM + ks * 32 + g * 8;
    const f32x4 a = *(const f32x4*)src;
    const f32x4 b = *(const f32x4*)(src + 4);
    float vals[8] = {a[0], a[1], a[2], a[3], b[0], b[1], b[2], b[3]};
    short8 o;
#pragma unroll
    for (int j = 0; j < 8; ++j) o[j] = (short)f2bf(vals[j]);
    *(short8*)(pk + (size_t)t * 16) = o;
}

// EXACT R6 structure (clean: 104 VGPR, FETCH 104MB, best time). Ten rounds of
// evidence: this pass ordering (Q->qreg->K->V->attn, two live LDS buffers,
// top-level passes, (256,2) bounds) is the only spill-free shape found; every
// reordering/fusion variant pushed the scheduler past the 128-VGPR occupancy
// boundary into GB-scale spill traffic. Only change vs R6: each 10-MFMA
// accumulation chain is split into independent lo/hi halves (+8 VGPR) to
// halve MFMA dependency-stall depth.
__global__ __launch_bounds__(THREADS, 2)
void temporal_attn_kernel(const float* __restrict__ hs,
                          const char* __restrict__ wpk,
                          const float* __restrict__ bo,
                          float* __restrict__ out)
{
    extern __shared__ __align__(16) char smem[];
    const int tid  = threadIdx.x;
    const int lane = tid & 63;
    const int wave = tid >> 6;
    const int g    = lane >> 4;
    const int lr   = lane & 15;

    const int seq = blockIdx.x * WPB + wave;
    const int bi  = seq >> 12;
    const int di  = seq & (DDIM - 1);

    char* const kbuf = smem + wave * 20480;   // Q, then K, then attn-out
    char* const vbuf = kbuf + 10240;          // V
    const char* const wl = wpk + lane * 16;

    // ---- load x rows, add PE, convert to bf16 A-fragments ----
    const float* xrow = hs + ((size_t)(bi * F + lr) * DDIM + di) * CDIM;
    short8 axk[KS];
#pragma unroll
    for (int ks = 0; ks < KS; ++ks) {
        const int k0 = ks * 32 + g * 8;
        const f32x4 a = __builtin_nontemporal_load((const f32x4*)(xrow + k0));
        const f32x4 b = __builtin_nontemporal_load((const f32x4*)(xrow + k0 + 4));
        float xv[8] = {a[0], a[1], a[2], a[3], b[0], b[1], b[2], b[3]};
#pragma unroll
        for (int jj = 0; jj < 4; ++jj) {
            const float c0 = (float)(k0 + 2 * jj);
            const float dv = __expf(c0 * -0.028782313662425575f); // -ln(1e4)/320
            const float ang = (float)lr * dv;                      // pos = frame
            xv[2 * jj]     += __sinf(ang);
            xv[2 * jj + 1] += __cosf(ang);
        }
        short8 t;
#pragma unroll
        for (int j = 0; j < 8; ++j) t[j] = (short)f2bf(xv[j]);
        axk[ks] = t;
    }

    // ---- projection pass, ping-pong pipelined over 20 n-tiles ----
    // loads for tile n+1 issue before the MFMAs of tile n; each tile's
    // accumulation is two independent 5-MFMA chains (halved dep latency).
    auto proj = [&](int m, char* dst) {
        const char* base = wl + (size_t)(m * NT) * KS * 1024;
        short8 fa[KS], fb[KS];
#pragma unroll
        for (int ks = 0; ks < KS; ++ks)
            fa[ks] = *(const short8*)(base + (size_t)ks * 1024);
#pragma unroll 1
        for (int np = 0; np < 10; ++np) {
#pragma unroll
            for (int ks = 0; ks < KS; ++ks)
                fb[ks] = *(const short8*)(base + (size_t)((2 * np + 1) * KS + ks) * 1024);
            f32x4 a0l = {0.f, 0.f, 0.f, 0.f}, a0h = {0.f, 0.f, 0.f, 0.f};
#pragma unroll
            for (int k5 = 0; k5 < 5; ++k5) {
                a0l = __builtin_amdgcn_mfma_f32_16x16x32_bf16(axk[k5],     fa[k5],     a0l, 0, 0, 0);
                a0h = __builtin_amdgcn_mfma_f32_16x16x32_bf16(axk[k5 + 5], fa[k5 + 5], a0h, 0, 0, 0);
            }
            const f32x4 a0 = a0l + a0h;
            if (np < 9) {
#pragma unroll
                for (int ks = 0; ks < KS; ++ks)
                    fa[ks] = *(const short8*)(base + (size_t)((2 * np + 2) * KS + ks) * 1024);
            }
            f32x4 a1l = {0.f, 0.f, 0.f, 0.f}, a1h = {0.f, 0.f, 0.f, 0.f};
#pragma unroll
            for (int k5 = 0; k5 < 5; ++k5) {
                a1l = __builtin_amdgcn_mfma_f32_16x16x32_bf16(axk[k5],     fb[k5],     a1l, 0, 0, 0);
                a1h = __builtin_amdgcn_mfma_f32_16x16x32_bf16(axk[k5 + 5], fb[k5 + 5], a1h, 0, 0, 0);
            }
            const f32x4 a1 = a1l + a1h;
#pragma unroll
            for (int r = 0; r < 4; ++r) {
                const int row = g * 4 + r;
                *(short*)(dst + swz(row, (2 * np * 16 + lr) * 2))       = (short)f2bf(a0[r]);
                *(short*)(dst + swz(row, ((2 * np + 1) * 16 + lr) * 2)) = (short)f2bf(a1[r]);
            }
        }
    };

    proj(0, kbuf);                       // Q -> kbuf (transient)
    short8 qreg[2][5];                   // statically indexed everywhere
#pragma unroll
    for (int h2 = 0; h2 < 2; ++h2)
#pragma unroll
        for (int j5 = 0; j5 < 5; ++j5)
            qreg[h2][j5] = *(const short8*)(kbuf + swz(lr, (g + 4 * h2) * 80 + j5 * 16));
    proj(1, kbuf);                       // K overwrites Q
    proj(2, vbuf);                       // V

    // ---- causal attention; lane = (q-row = lr, head = g + 4*h2) ----
    // h2 fully unrolled (attention only, no global loads -> small region).
    // h2=0 writes attn-out into kbuf chunks {0..19}^r; h2=1 reads K chunks
    // {20..39}^r -- disjoint since chunk^r is a bijection.
    const float scale = 0.15811388300841897f;  // 40^-0.5
#pragma unroll
    for (int h2 = 0; h2 < 2; ++h2) {
        const int cb = (g + 4 * h2) * 80;
        float s[F];
#pragma unroll
        for (int kk = 0; kk < F; ++kk) s[kk] = 0.f;
#pragma unroll
        for (int j5 = 0; j5 < 5; ++j5) {
            float qf[8];
#pragma unroll
            for (int j = 0; j < 8; ++j) qf[j] = bf2f((unsigned short)qreg[h2][j5][j]);
#pragma unroll
            for (int kk = 0; kk < F; ++kk) {
                short8 k8 = *(const short8*)(kbuf + swz(kk, cb + j5 * 16));
#pragma unroll
                for (int j = 0; j < 8; ++j) s[kk] += qf[j] * bf2f((unsigned short)k8[j]);
            }
        }
        float m = -1e30f;
#pragma unroll
        for (int kk = 0; kk < F; ++kk) {
            s[kk] = (kk <= lr) ? s[kk] * scale : -1e30f;
            m = fmaxf(m, s[kk]);
        }
        float sum = 0.f;
#pragma unroll
        for (int kk = 0; kk < F; ++kk) { s[kk] = __expf(s[kk] - m); sum += s[kk]; }
        const float inv = 1.f / sum;
#pragma unroll
        for (int kk = 0; kk < F; ++kk) s[kk] *= inv;

        // PV chunked: one 8-wide d-chunk at a time, packed straight to LDS
#pragma unroll
        for (int j5 = 0; j5 < 5; ++j5) {
            float a8[8];
#pragma unroll
            for (int j = 0; j < 8; ++j) a8[j] = 0.f;
#pragma unroll
            for (int kk = 0; kk < F; ++kk) {
                short8 v8 = *(const short8*)(vbuf + swz(kk, cb + j5 * 16));
#pragma unroll
                for (int j = 0; j < 8; ++j) a8[j] += s[kk] * bf2f((unsigned short)v8[j]);
            }
            short8 t;
#pragma unroll
            for (int j = 0; j < 8; ++j) t[j] = (short)f2bf(a8[j]);
            *(short8*)(kbuf + swz(lr, cb + j5 * 16)) = t;
        }
    }

    // ---- output projection: out = ao @ Wo.T + bo, pipelined + paired stores ----
    short8 aof[KS];
#pragma unroll
    for (int ks = 0; ks < KS; ++ks)
        aof[ks] = *(const short8*)(kbuf + swz(lr, ks * 64 + g * 16));

    {
        const char* base = wl + (size_t)(3 * NT) * KS * 1024;
        short8 fa[KS], fb[KS];
#pragma unroll
        for (int ks = 0; ks < KS; ++ks)
            fa[ks] = *(const short8*)(base + (size_t)ks * 1024);
#pragma unroll 1
        for (int np = 0; np < 10; ++np) {
#pragma unroll
            for (int ks = 0; ks < KS; ++ks)
                fb[ks] = *(const short8*)(base + (size_t)((2 * np + 1) * KS + ks) * 1024);
            f32x4 a0l = {0.f, 0.f, 0.f, 0.f}, a0h = {0.f, 0.f, 0.f, 0.f};
#pragma unroll
            for (int k5 = 0; k5 < 5; ++k5) {
                a0l = __builtin_amdgcn_mfma_f32_16x16x32_bf16(aof[k5],     fa[k5],     a0l, 0, 0, 0);
                a0h = __builtin_amdgcn_mfma_f32_16x16x32_bf16(aof[k5 + 5], fa[k5 + 5], a0h, 0, 0, 0);
            }
            const f32x4 a0 = a0l + a0h;
            if (np < 9) {
#pragma unroll
                for (int ks = 0; ks < KS; ++ks)
                    fa[ks] = *(const short8*)(base + (size_t)((2 * np + 2) * KS + ks) * 1024);
            }
            f32x4 a1l = {0.f, 0.f, 0.f, 0.f}, a1h = {0.f, 0.f, 0.f, 0.f};
#pragma unroll
            for (int k5 = 0; k5 < 5; ++k5) {
                a1l = __builtin_amdgcn_mfma_f32_16x16x32_bf16(aof[k5],     fb[k5],     a1l, 0, 0, 0);
                a1h = __builtin_amdgcn_mfma_f32_16x16x32_bf16(aof[k5 + 5], fb[k5 + 5], a1h, 0, 0, 0);
            }
            const f32x4 a1 = a1l + a1h;

            const int c0 = 2 * np * 16 + lr;
            const int c1 = c0 + 16;
            const float bias0 = bo[c0];
            const float bias1 = bo[c1];
            // rows are 1280B-aligned; pair np covers bytes [np*128, +128):
            // exactly one full 128B line per output row, no write amp.
#pragma unroll
            for (int r = 0; r < 4; ++r) {
                float* rowp = out + ((size_t)(bi * F + g * 4 + r) * DDIM + di) * CDIM;
                rowp[c0] = a0[r] + bias0;
                rowp[c1] = a1[r] + bias1;
            }
        }
    }
}

extern "C" void kernel_launch(void* const* d_in, const int* in_sizes, int n_in,
                              void* d_out, int out_size, void* d_ws, size_t ws_size,
                              hipStream_t stream) {
    const float* hs = (const float*)d_in[0];
    const float* Wq = (const float*)d_in[1];
    const float* Wk = (const float*)d_in[2];
    const float* Wv = (const float*)d_in[3];
    const float* Wo = (const float*)d_in[4];
    const float* bo = (const float*)d_in[5];
    float* out = (float*)d_out;
    char* wpk = (char*)d_ws;   // 4*200*1024 = 819200 B of packed bf16 weights

    pack_weights_kernel<<<dim3((4 * NT * KS * 64 + 255) / 256), dim3(256), 0, stream>>>(
        Wq, Wk, Wv, Wo, wpk);

    const int lds = WPB * 20480;   // 81920 B -> 2 blocks/CU (8 waves/CU)
    (void)hipFuncSetAttribute((const void*)temporal_attn_kernel,
                              hipFuncAttributeMaxDynamicSharedMemorySize, lds);
    temporal_attn_kernel<<<dim3(NSEQ / WPB), dim3(THREADS), lds, stream>>>(
        hs, wpk, bo, out);
}